// Round 2
// baseline (6613.882 us; speedup 1.0000x reference)
//
#include <hip/hip_runtime.h>
#include <math.h>

#define TPB 256

typedef __attribute__((ext_vector_type(8))) unsigned short ushort8;

__device__ __forceinline__ float b2f(unsigned short u) {
  union { unsigned int i; float f; } c; c.i = ((unsigned int)u) << 16; return c.f;
}
__device__ __forceinline__ unsigned short f2b(float f) {
  union { float f; unsigned int i; } c; c.f = f;
  unsigned int x = c.i;
  x += 0x7FFFu + ((x >> 16) & 1u);           // round-to-nearest-even
  return (unsigned short)(x >> 16);
}

// XOR swizzle for LDS float4 tiles [64 rows][16 f4]
__device__ __forceinline__ int swz(int row, int f4) {
  return (row << 4) + (f4 ^ ((row >> 2) & 7));
}

// ---------------- CSR build ----------------
__global__ void k_hist(const int* __restrict__ dst, int* deg, int E) {
  int e = blockIdx.x * TPB + threadIdx.x;
  if (e < E) atomicAdd(&deg[dst[e]], 1);
}

__global__ void k_gcnt(const int* __restrict__ batch, int* gcnt, int N) {
  int t = blockIdx.x * TPB + threadIdx.x;
  int n0 = t * 16;
  if (n0 >= N) return;
  int n1 = min(n0 + 16, N);
  int cur = batch[n0];
  int c = 0;
  for (int n = n0; n < n1; ++n) {
    int b = batch[n];
    if (b != cur) { atomicAdd(&gcnt[cur], c); cur = b; c = 0; }
    ++c;
  }
  atomicAdd(&gcnt[cur], c);
}

__global__ void k_scan1(int* data, int* bsum, int N) {
  __shared__ int s[TPB];
  int t = threadIdx.x;
  int i = blockIdx.x * TPB + t;
  int v = (i < N) ? data[i] : 0;
  s[t] = v;
  __syncthreads();
  for (int d = 1; d < TPB; d <<= 1) {
    int u = (t >= d) ? s[t - d] : 0;
    __syncthreads();
    s[t] += u;
    __syncthreads();
  }
  if (i < N) data[i] = s[t] - v;
  if (t == TPB - 1) bsum[blockIdx.x] = s[t];
}

__global__ void k_scan2(const int* bsum, int* boff, int nb) {
  __shared__ int s[1024];
  int t = threadIdx.x;
  int v = (t < nb) ? bsum[t] : 0;
  s[t] = v;
  __syncthreads();
  for (int d = 1; d < 1024; d <<= 1) {
    int u = (t >= d) ? s[t - d] : 0;
    __syncthreads();
    s[t] += u;
    __syncthreads();
  }
  if (t < nb) boff[t] = s[t] - v;
}

__global__ void k_scan3(int* rp, const int* __restrict__ boff, int* cursor, int N, int E) {
  int i = blockIdx.x * TPB + threadIdx.x;
  if (i < N) {
    int v = rp[i] + boff[i >> 8];
    rp[i] = v;
    cursor[i] = v;
  } else if (i == N) {
    rp[N] = E;
  }
}

__global__ void k_fill(const int* __restrict__ src, const int* __restrict__ dst,
                       int* cursor, int* __restrict__ csr, int E) {
  int e = blockIdx.x * TPB + threadIdx.x;
  if (e < E) {
    int p = atomicAdd(&cursor[dst[e]], 1);
    csr[p] = src[e];
  }
}

// ---------------- Layer 1 (F=1) ----------------
__global__ void k_agg1(const float4* __restrict__ x, const int* __restrict__ rp,
                       const int* __restrict__ csr, float4* __restrict__ agg1, int N) {
  int n = blockIdx.x * TPB + threadIdx.x;
  if (n >= N) return;
  int b = rp[n], e = rp[n + 1];
  float4 a = make_float4(0.f, 0.f, 0.f, 0.f);
  for (int i = b; i < e; ++i) {
    float4 v = x[csr[i]];
    a.x += v.x; a.y += v.y; a.z += v.z; a.w += v.w;
  }
  float inv = (e > b) ? 1.f / (float)(e - b) : 0.f;
  a.x *= inv; a.y *= inv; a.z *= inv; a.w *= inv;
  agg1[n] = a;
}

// h1[r*64+c] = relu(agg1[r]*W1l[c] + b1l[c] + x[r]*W1r[c]), bf16 out
__global__ void k_l1(const float* __restrict__ x, const float* __restrict__ agg1,
                     const float* __restrict__ W1l, const float* __restrict__ b1l,
                     const float* __restrict__ W1r, unsigned short* __restrict__ h, int rows) {
  int q = blockIdx.x * TPB + threadIdx.x;       // thread = (row, 8-col group)
  if (q >= rows * 8) return;
  int r = q >> 3, c8 = (q & 7) * 8;
  float a = agg1[r], xx = x[r];
  ushort8 o;
#pragma unroll
  for (int k = 0; k < 8; ++k) {
    float v = fmaxf(a * W1l[c8 + k] + b1l[c8 + k] + xx * W1r[c8 + k], 0.f);
    o[k] = f2b(v);
  }
  *(ushort8*)(h + (size_t)r * 64 + c8) = o;
}

// ---------------- Fused layer: mean-agg (gather) + dual GEMM + bias + relu ----------------
// Block: 256 threads = 4 waves, 16 nodes = 64 GEMM rows. hIn/hOut bf16 [N][256].
#define DOT4(ACC, A4, W4) ACC += A4.x * W4.x + A4.y * W4.y + A4.z * W4.z + A4.w * W4.w

__global__ __launch_bounds__(256) void k_layer(
    const unsigned short* __restrict__ hIn, const int* __restrict__ rp,
    const int* __restrict__ csr,
    const float4* __restrict__ Wl, const float4* __restrict__ Wr,
    const float* __restrict__ bias, unsigned short* __restrict__ hOut, int N) {
  __shared__ float4 As[1024], Hs[1024], Wls[1024], Wrs[1024];
  int t = threadIdx.x;
  int n0 = blockIdx.x * 16;
  int rows = N * 4;
  int r0 = blockIdx.x * 64;

  // weights -> LDS (fp32)
#pragma unroll
  for (int k = 0; k < 4; ++k) {
    int idx = k * TPB + t;
    int c = idx >> 4, f4 = idx & 15;
    Wls[swz(c, f4)] = Wl[idx];
    Wrs[swz(c, f4)] = Wr[idx];
  }

  // own H rows -> LDS (bf16 -> fp32). thread t: row t>>2, f4 group (t&3)*4..+3
  {
    int rr = t >> 2;
    int r = r0 + rr;
    int f40 = (t & 3) * 4;
    if (r < rows) {
      const unsigned short* base = hIn + (size_t)r * 64 + (t & 3) * 16;
      ushort8 v0 = *(const ushort8*)(base);
      ushort8 v1 = *(const ushort8*)(base + 8);
      Hs[swz(rr, f40 + 0)] = make_float4(b2f(v0[0]), b2f(v0[1]), b2f(v0[2]), b2f(v0[3]));
      Hs[swz(rr, f40 + 1)] = make_float4(b2f(v0[4]), b2f(v0[5]), b2f(v0[6]), b2f(v0[7]));
      Hs[swz(rr, f40 + 2)] = make_float4(b2f(v1[0]), b2f(v1[1]), b2f(v1[2]), b2f(v1[3]));
      Hs[swz(rr, f40 + 3)] = make_float4(b2f(v1[4]), b2f(v1[5]), b2f(v1[6]), b2f(v1[7]));
    } else {
      float4 z = make_float4(0.f, 0.f, 0.f, 0.f);
      Hs[swz(rr, f40 + 0)] = z; Hs[swz(rr, f40 + 1)] = z;
      Hs[swz(rr, f40 + 2)] = z; Hs[swz(rr, f40 + 3)] = z;
    }
  }

  // aggregation: wave w handles nodes n0 + w*4 .. +3; lane owns 4 floats of the 256-row
  {
    int wave = t >> 6, lane = t & 63;
#pragma unroll
    for (int k = 0; k < 4; ++k) {
      int nl = wave * 4 + k;
      int n = n0 + nl;
      float a0 = 0.f, a1 = 0.f, a2 = 0.f, a3 = 0.f;
      float inv = 0.f;
      if (n < N) {
        int b = rp[n], e = rp[n + 1];
        int i = b;
        for (; i + 1 < e; i += 2) {
          int s0 = csr[i], s1 = csr[i + 1];
          ushort4 u0 = *(const ushort4*)(hIn + (size_t)s0 * 256 + lane * 4);
          ushort4 u1 = *(const ushort4*)(hIn + (size_t)s1 * 256 + lane * 4);
          a0 += b2f(u0.x) + b2f(u1.x);
          a1 += b2f(u0.y) + b2f(u1.y);
          a2 += b2f(u0.z) + b2f(u1.z);
          a3 += b2f(u0.w) + b2f(u1.w);
        }
        if (i < e) {
          ushort4 u0 = *(const ushort4*)(hIn + (size_t)csr[i] * 256 + lane * 4);
          a0 += b2f(u0.x); a1 += b2f(u0.y); a2 += b2f(u0.z); a3 += b2f(u0.w);
        }
        inv = (e > b) ? 1.f / (float)(e - b) : 0.f;
      }
      As[swz(nl * 4 + (lane >> 4), lane & 15)] =
          make_float4(a0 * inv, a1 * inv, a2 * inv, a3 * inv);
    }
  }
  __syncthreads();

  // dual GEMM 64x64: thread = 4 rows x 4 cols
  int tr = t >> 4, tc = t & 15;
  float4 bl4 = ((const float4*)bias)[tc];
  float bb[4] = {bl4.x, bl4.y, bl4.z, bl4.w};
  float acc[4][4];
#pragma unroll
  for (int i = 0; i < 4; ++i)
#pragma unroll
    for (int j = 0; j < 4; ++j) acc[i][j] = bb[j];

#pragma unroll
  for (int f4 = 0; f4 < 16; ++f4) {
    float4 a0 = As[swz(tr * 4 + 0, f4)];
    float4 a1 = As[swz(tr * 4 + 1, f4)];
    float4 a2 = As[swz(tr * 4 + 2, f4)];
    float4 a3 = As[swz(tr * 4 + 3, f4)];
    float4 h0 = Hs[swz(tr * 4 + 0, f4)];
    float4 h1 = Hs[swz(tr * 4 + 1, f4)];
    float4 h2 = Hs[swz(tr * 4 + 2, f4)];
    float4 h3 = Hs[swz(tr * 4 + 3, f4)];
    float4 l0 = Wls[swz(tc * 4 + 0, f4)];
    float4 l1 = Wls[swz(tc * 4 + 1, f4)];
    float4 l2 = Wls[swz(tc * 4 + 2, f4)];
    float4 l3 = Wls[swz(tc * 4 + 3, f4)];
    float4 r0v = Wrs[swz(tc * 4 + 0, f4)];
    float4 r1v = Wrs[swz(tc * 4 + 1, f4)];
    float4 r2v = Wrs[swz(tc * 4 + 2, f4)];
    float4 r3v = Wrs[swz(tc * 4 + 3, f4)];
    DOT4(acc[0][0], a0, l0); DOT4(acc[0][1], a0, l1); DOT4(acc[0][2], a0, l2); DOT4(acc[0][3], a0, l3);
    DOT4(acc[1][0], a1, l0); DOT4(acc[1][1], a1, l1); DOT4(acc[1][2], a1, l2); DOT4(acc[1][3], a1, l3);
    DOT4(acc[2][0], a2, l0); DOT4(acc[2][1], a2, l1); DOT4(acc[2][2], a2, l2); DOT4(acc[2][3], a2, l3);
    DOT4(acc[3][0], a3, l0); DOT4(acc[3][1], a3, l1); DOT4(acc[3][2], a3, l2); DOT4(acc[3][3], a3, l3);
    DOT4(acc[0][0], h0, r0v); DOT4(acc[0][1], h0, r1v); DOT4(acc[0][2], h0, r2v); DOT4(acc[0][3], h0, r3v);
    DOT4(acc[1][0], h1, r0v); DOT4(acc[1][1], h1, r1v); DOT4(acc[1][2], h1, r2v); DOT4(acc[1][3], h1, r3v);
    DOT4(acc[2][0], h2, r0v); DOT4(acc[2][1], h2, r1v); DOT4(acc[2][2], h2, r2v); DOT4(acc[2][3], h2, r3v);
    DOT4(acc[3][0], h3, r0v); DOT4(acc[3][1], h3, r1v); DOT4(acc[3][2], h3, r2v); DOT4(acc[3][3], h3, r3v);
  }

#pragma unroll
  for (int i = 0; i < 4; ++i) {
    int r = r0 + tr * 4 + i;
    if (r < rows) {
      ushort4 o;
      o.x = f2b(fmaxf(acc[i][0], 0.f));
      o.y = f2b(fmaxf(acc[i][1], 0.f));
      o.z = f2b(fmaxf(acc[i][2], 0.f));
      o.w = f2b(fmaxf(acc[i][3], 0.f));
      *(ushort4*)(hOut + (size_t)r * 64 + tc * 4) = o;
    }
  }
}

// ---------------- Pooling (batch sorted: run-length accumulate), bf16 in ----------------
__global__ void k_pool(const unsigned short* __restrict__ h, const int* __restrict__ batch,
                       float* pooled, int N) {
  int t = threadIdx.x;
  int nPer = (N + gridDim.x - 1) / gridDim.x;
  int n0 = blockIdx.x * nPer;
  int n1 = min(N, n0 + nPer);
  if (n0 >= n1) return;
  float acc = 0.f;
  int cur = batch[n0];
  for (int n = n0; n < n1; ++n) {
    int b = batch[n];
    if (b != cur) {
      atomicAdd(&pooled[cur * 256 + t], acc);
      acc = 0.f;
      cur = b;
    }
    acc += b2f(h[(size_t)n * 256 + t]);
  }
  atomicAdd(&pooled[cur * 256 + t], acc);
}

__global__ void k_final(const float* __restrict__ pooled, const int* __restrict__ gcnt,
                        const float* __restrict__ Wlin, const float* __restrict__ blin,
                        float* __restrict__ out, int B) {
  int t = blockIdx.x * TPB + threadIdx.x;
  int b = t >> 2, j = t & 3;
  if (b >= B) return;
  float inv = 1.f / fmaxf((float)gcnt[b], 1.f);
  float s = blin[0];
  const float* p = pooled + b * 256 + j * 64;
#pragma unroll
  for (int f = 0; f < 64; ++f) s += p[f] * inv * Wlin[f];
  float z = 1.f / (1.f + expf(-s));
  z += __shfl_xor(z, 1);
  z += __shfl_xor(z, 2);
  if (j == 0) out[b] = 0.25f * z;
}

// ---------------- Host launcher ----------------
extern "C" void kernel_launch(void* const* d_in, const int* in_sizes, int n_in,
                              void* d_out, int out_size, void* d_ws, size_t ws_size,
                              hipStream_t stream) {
  const float* x   = (const float*)d_in[0];
  const int* edge  = (const int*)d_in[1];
  const int* batch = (const int*)d_in[2];
  const float* W1l = (const float*)d_in[3];
  const float* b1l = (const float*)d_in[4];
  const float* W1r = (const float*)d_in[5];
  const float* W2l = (const float*)d_in[6];
  const float* b2l = (const float*)d_in[7];
  const float* W2r = (const float*)d_in[8];
  const float* W3l = (const float*)d_in[9];
  const float* b3l = (const float*)d_in[10];
  const float* W3r = (const float*)d_in[11];
  const float* Wlin = (const float*)d_in[12];
  const float* blin = (const float*)d_in[13];
  float* out = (float*)d_out;

  const int N = in_sizes[0] / 4;          // x: [N,1,4]
  const int E = in_sizes[1] / 2;          // edge_index: [2,E]
  const int B = out_size;
  const int rows = 4 * N;

  const int* srcA = edge;
  const int* dstA = edge + E;

  // workspace carve (~109 MB total)
  char* p = (char*)d_ws;
  auto carve = [&](size_t bytes) -> void* {
    void* r = (void*)p;
    p += (bytes + 255) & ~(size_t)255;
    return r;
  };
  int* rp      = (int*)carve((size_t)(N + 1) * 4);
  int* cursor  = (int*)carve((size_t)N * 4);
  int* bsum    = (int*)carve(4096);
  int* boff    = (int*)carve(4096);
  int* gcnt    = (int*)carve((size_t)B * 4);
  int* csr     = (int*)carve((size_t)E * 4);
  float* agg1  = (float*)carve((size_t)N * 4 * 4);
  float* pooled = (float*)carve((size_t)B * 256 * 4);
  unsigned short* hA = (unsigned short*)carve((size_t)N * 256 * 2);
  unsigned short* hB = (unsigned short*)carve((size_t)N * 256 * 2);
  (void)ws_size; (void)n_in;

  hipMemsetAsync(rp, 0, (size_t)N * 4, stream);
  hipMemsetAsync(gcnt, 0, (size_t)B * 4, stream);
  hipMemsetAsync(pooled, 0, (size_t)B * 256 * 4, stream);

  int nbScan = (N + TPB - 1) / TPB;

  k_hist<<<(E + TPB - 1) / TPB, TPB, 0, stream>>>(dstA, rp, E);
  k_gcnt<<<((N + 15) / 16 + TPB - 1) / TPB, TPB, 0, stream>>>(batch, gcnt, N);
  k_scan1<<<nbScan, TPB, 0, stream>>>(rp, bsum, N);
  k_scan2<<<1, 1024, 0, stream>>>(bsum, boff, nbScan);
  k_scan3<<<(N + 1 + TPB - 1) / TPB, TPB, 0, stream>>>(rp, boff, cursor, N, E);
  k_fill<<<(E + TPB - 1) / TPB, TPB, 0, stream>>>(srcA, dstA, cursor, csr, E);

  // layer 1 (F=1)
  k_agg1<<<(N + TPB - 1) / TPB, TPB, 0, stream>>>((const float4*)x, rp, csr, (float4*)agg1, N);
  k_l1<<<((size_t)rows * 8 + TPB - 1) / TPB, TPB, 0, stream>>>(x, agg1, W1l, b1l, W1r, hA, rows);

  // layers 2 & 3: fused gather + dual GEMM
  int nbLayer = (N + 15) / 16;
  k_layer<<<nbLayer, TPB, 0, stream>>>(hA, rp, csr, (const float4*)W2l, (const float4*)W2r,
                                       b2l, hB, N);
  k_layer<<<nbLayer, TPB, 0, stream>>>(hB, rp, csr, (const float4*)W3l, (const float4*)W3r,
                                       b3l, hA, N);

  // pooling + head
  k_pool<<<512, TPB, 0, stream>>>(hA, batch, pooled, N);
  k_final<<<(B * 4 + TPB - 1) / TPB, TPB, 0, stream>>>(pooled, gcnt, Wlin, blin, out, B);
}

// Round 3
// 529.835 us; speedup vs baseline: 12.4829x; 12.4829x over previous
//
#include <hip/hip_runtime.h>
#include <math.h>

#define TPB 256

typedef unsigned short ushort_t;
typedef __attribute__((ext_vector_type(8))) short short8v;     // 8 bf16 (4 VGPRs), MFMA A/B frag
typedef __attribute__((ext_vector_type(4))) float f32x4;       // MFMA C/D frag
typedef __attribute__((ext_vector_type(8))) unsigned short ushort8;

__device__ __forceinline__ float b2f(unsigned short u) {
  union { unsigned int i; float f; } c; c.i = ((unsigned int)u) << 16; return c.f;
}
__device__ __forceinline__ unsigned short f2b(float f) {
  union { float f; unsigned int i; } c; c.f = f;
  unsigned int x = c.i;
  x += 0x7FFFu + ((x >> 16) & 1u);           // round-to-nearest-even
  return (unsigned short)(x >> 16);
}

// ---------------- CSR build ----------------
__global__ void k_hist(const int* __restrict__ dst, int* deg, int E) {
  int e = blockIdx.x * TPB + threadIdx.x;
  if (e < E) atomicAdd(&deg[dst[e]], 1);
}

__global__ void k_gcnt(const int* __restrict__ batch, int* gcnt, int N) {
  int t = blockIdx.x * TPB + threadIdx.x;
  int n0 = t * 16;
  if (n0 >= N) return;
  int n1 = min(n0 + 16, N);
  int cur = batch[n0];
  int c = 0;
  for (int n = n0; n < n1; ++n) {
    int b = batch[n];
    if (b != cur) { atomicAdd(&gcnt[cur], c); cur = b; c = 0; }
    ++c;
  }
  atomicAdd(&gcnt[cur], c);
}

__global__ void k_scan1(int* data, int* bsum, int N) {
  __shared__ int s[TPB];
  int t = threadIdx.x;
  int i = blockIdx.x * TPB + t;
  int v = (i < N) ? data[i] : 0;
  s[t] = v;
  __syncthreads();
  for (int d = 1; d < TPB; d <<= 1) {
    int u = (t >= d) ? s[t - d] : 0;
    __syncthreads();
    s[t] += u;
    __syncthreads();
  }
  if (i < N) data[i] = s[t] - v;
  if (t == TPB - 1) bsum[blockIdx.x] = s[t];
}

__global__ void k_scan2(const int* bsum, int* boff, int nb) {
  __shared__ int s[1024];
  int t = threadIdx.x;
  int v = (t < nb) ? bsum[t] : 0;
  s[t] = v;
  __syncthreads();
  for (int d = 1; d < 1024; d <<= 1) {
    int u = (t >= d) ? s[t - d] : 0;
    __syncthreads();
    s[t] += u;
    __syncthreads();
  }
  if (t < nb) boff[t] = s[t] - v;
}

__global__ void k_scan3(int* rp, const int* __restrict__ boff, int* cursor, int N, int E) {
  int i = blockIdx.x * TPB + threadIdx.x;
  if (i < N) {
    int v = rp[i] + boff[i >> 8];
    rp[i] = v;
    cursor[i] = v;
  } else if (i == N) {
    rp[N] = E;
  }
}

__global__ void k_fill(const int* __restrict__ src, const int* __restrict__ dst,
                       int* cursor, int* __restrict__ csr, int E) {
  int e = blockIdx.x * TPB + threadIdx.x;
  if (e < E) {
    int p = atomicAdd(&cursor[dst[e]], 1);
    csr[p] = src[e];
  }
}

// ---------------- weight fp32 -> bf16 ----------------
__global__ void k_cvtw(const float* __restrict__ s0, const float* __restrict__ s1,
                       const float* __restrict__ s2, const float* __restrict__ s3,
                       ushort_t* d0, ushort_t* d1, ushort_t* d2, ushort_t* d3, int n) {
  int i = blockIdx.x * TPB + threadIdx.x;
  if (i < n) { d0[i] = f2b(s0[i]); d1[i] = f2b(s1[i]); d2[i] = f2b(s2[i]); d3[i] = f2b(s3[i]); }
}

// ---------------- Layer 1 (F=1) ----------------
__global__ void k_agg1(const float4* __restrict__ x, const int* __restrict__ rp,
                       const int* __restrict__ csr, float4* __restrict__ agg1, int N) {
  int n = blockIdx.x * TPB + threadIdx.x;
  if (n >= N) return;
  int b = rp[n], e = rp[n + 1];
  float4 a = make_float4(0.f, 0.f, 0.f, 0.f);
  for (int i = b; i < e; ++i) {
    float4 v = x[csr[i]];
    a.x += v.x; a.y += v.y; a.z += v.z; a.w += v.w;
  }
  float inv = (e > b) ? 1.f / (float)(e - b) : 0.f;
  a.x *= inv; a.y *= inv; a.z *= inv; a.w *= inv;
  agg1[n] = a;
}

// h1 flat[(n*4+m)*64 + c] = relu(agg1[n*4+m]*W1l[c] + b1l[c] + x[n*4+m]*W1r[c]), bf16 out
__global__ void k_l1(const float* __restrict__ x, const float* __restrict__ agg1,
                     const float* __restrict__ W1l, const float* __restrict__ b1l,
                     const float* __restrict__ W1r, ushort_t* __restrict__ h, int rows) {
  int q = blockIdx.x * TPB + threadIdx.x;       // thread = (row, 8-col group)
  if (q >= rows * 8) return;
  int r = q >> 3, c8 = (q & 7) * 8;
  float a = agg1[r], xx = x[r];
  ushort8 o;
#pragma unroll
  for (int k = 0; k < 8; ++k) {
    float v = fmaxf(a * W1l[c8 + k] + b1l[c8 + k] + xx * W1r[c8 + k], 0.f);
    o[k] = f2b(v);
  }
  *(ushort8*)(h + (size_t)r * 64 + c8) = o;
}

// ---------------- Fused layer: mean-agg gather + dual MFMA GEMM + bias + relu ----------
// Block: 256 threads = 4 waves = 16 nodes = 64 GEMM rows. h flat viewed [4N][64] bf16.
// Wave w: aggregates nodes n0+w*4..+3 (rows w*16..+15), then computes its 16x64 output.
__global__ __launch_bounds__(256) void k_layer(
    const ushort_t* __restrict__ hIn, const int* __restrict__ rp,
    const int* __restrict__ csr,
    const ushort_t* __restrict__ Wlb, const ushort_t* __restrict__ Wrb,
    const float* __restrict__ bias, ushort_t* __restrict__ hOut, int N) {
  __shared__ ushort_t As[4096];                 // [64 rows][64 bf16], XOR-swizzled
  int t = threadIdx.x;
  int wave = t >> 6, lane = t & 63;
  int g = lane >> 4, l15 = lane & 15;
  int n0 = blockIdx.x * 16;
  int r0 = blockIdx.x * 64;
  int rows = N * 4;

  // ---- aggregation: wave handles 4 nodes; lane owns flat cols lane*4..+3 ----
#pragma unroll
  for (int k = 0; k < 4; ++k) {
    int nl = wave * 4 + k;
    int n = n0 + nl;
    float a0 = 0.f, a1 = 0.f, a2 = 0.f, a3 = 0.f, inv = 0.f;
    if (n < N) {
      int b = rp[n], e = rp[n + 1];
      int i = b;
      for (; i + 1 < e; i += 2) {
        int s0 = csr[i], s1 = csr[i + 1];
        ushort4 u0 = *(const ushort4*)(hIn + (size_t)s0 * 256 + lane * 4);
        ushort4 u1 = *(const ushort4*)(hIn + (size_t)s1 * 256 + lane * 4);
        a0 += b2f(u0.x) + b2f(u1.x);
        a1 += b2f(u0.y) + b2f(u1.y);
        a2 += b2f(u0.z) + b2f(u1.z);
        a3 += b2f(u0.w) + b2f(u1.w);
      }
      if (i < e) {
        ushort4 u0 = *(const ushort4*)(hIn + (size_t)csr[i] * 256 + lane * 4);
        a0 += b2f(u0.x); a1 += b2f(u0.y); a2 += b2f(u0.z); a3 += b2f(u0.w);
      }
      inv = (e > b) ? 1.f / (float)(e - b) : 0.f;
    }
    ushort4 pk;
    pk.x = f2b(a0 * inv); pk.y = f2b(a1 * inv); pk.z = f2b(a2 * inv); pk.w = f2b(a3 * inv);
    int row = nl * 4 + g;                      // GEMM row within tile
    int cb = l15 * 8;                          // byte col within 128B row
    *(ushort4*)((char*)As + row * 128 + (cb ^ ((row & 7) << 4))) = pk;
  }
  __syncthreads();

  // ---- fragments ----
  int arow = wave * 16 + l15;                  // A frag: row=lane&15, k=(lane>>4)*8+e
  short8v af0 = *(const short8v*)((char*)As + arow * 128 + (((g * 16) + 0) ^ ((arow & 7) << 4)));
  short8v af1 = *(const short8v*)((char*)As + arow * 128 + (((g * 16) + 64) ^ ((arow & 7) << 4)));

  int rbase = r0 + wave * 16 + l15;
  if (rbase > rows - 1) rbase = rows - 1;      // clamp (N multiple of 16 in practice)
  const ushort_t* hrow = hIn + (size_t)rbase * 64;
  short8v hf0 = *(const short8v*)(hrow + g * 8);
  short8v hf1 = *(const short8v*)(hrow + 32 + g * 8);

  f32x4 acc[4];
#pragma unroll
  for (int c = 0; c < 4; ++c) {
    float bv = bias[c * 16 + l15];
    acc[c] = (f32x4){bv, bv, bv, bv};
    const ushort_t* wl = Wlb + (size_t)(c * 16 + l15) * 64;
    const ushort_t* wr = Wrb + (size_t)(c * 16 + l15) * 64;
    short8v bl0 = *(const short8v*)(wl + g * 8);
    short8v bl1 = *(const short8v*)(wl + 32 + g * 8);
    short8v br0 = *(const short8v*)(wr + g * 8);
    short8v br1 = *(const short8v*)(wr + 32 + g * 8);
    acc[c] = __builtin_amdgcn_mfma_f32_16x16x32_bf16(af0, bl0, acc[c], 0, 0, 0);
    acc[c] = __builtin_amdgcn_mfma_f32_16x16x32_bf16(af1, bl1, acc[c], 0, 0, 0);
    acc[c] = __builtin_amdgcn_mfma_f32_16x16x32_bf16(hf0, br0, acc[c], 0, 0, 0);
    acc[c] = __builtin_amdgcn_mfma_f32_16x16x32_bf16(hf1, br1, acc[c], 0, 0, 0);
  }

  // ---- C/D: col = lane&15, row = (lane>>4)*4 + reg ----
#pragma unroll
  for (int c = 0; c < 4; ++c) {
#pragma unroll
    for (int i = 0; i < 4; ++i) {
      int grow = r0 + wave * 16 + g * 4 + i;
      if (grow < rows)
        hOut[(size_t)grow * 64 + c * 16 + l15] = f2b(fmaxf(acc[c][i], 0.f));
    }
  }
}

// ---------------- Pooling (batch sorted: run-length accumulate), bf16 in ----------------
__global__ void k_pool(const ushort_t* __restrict__ h, const int* __restrict__ batch,
                       float* pooled, int N) {
  int t = threadIdx.x;
  int nPer = (N + gridDim.x - 1) / gridDim.x;
  int n0 = blockIdx.x * nPer;
  int n1 = min(N, n0 + nPer);
  if (n0 >= n1) return;
  float acc = 0.f;
  int cur = batch[n0];
  for (int n = n0; n < n1; ++n) {
    int b = batch[n];
    if (b != cur) {
      atomicAdd(&pooled[cur * 256 + t], acc);
      acc = 0.f;
      cur = b;
    }
    acc += b2f(h[(size_t)n * 256 + t]);
  }
  atomicAdd(&pooled[cur * 256 + t], acc);
}

__global__ void k_final(const float* __restrict__ pooled, const int* __restrict__ gcnt,
                        const float* __restrict__ Wlin, const float* __restrict__ blin,
                        float* __restrict__ out, int B) {
  int t = blockIdx.x * TPB + threadIdx.x;
  int b = t >> 2, j = t & 3;
  if (b >= B) return;
  float inv = 1.f / fmaxf((float)gcnt[b], 1.f);
  float s = blin[0];
  const float* p = pooled + b * 256 + j * 64;
#pragma unroll
  for (int f = 0; f < 64; ++f) s += p[f] * inv * Wlin[f];
  float z = 1.f / (1.f + expf(-s));
  z += __shfl_xor(z, 1);
  z += __shfl_xor(z, 2);
  if (j == 0) out[b] = 0.25f * z;
}

// ---------------- Host launcher ----------------
extern "C" void kernel_launch(void* const* d_in, const int* in_sizes, int n_in,
                              void* d_out, int out_size, void* d_ws, size_t ws_size,
                              hipStream_t stream) {
  const float* x   = (const float*)d_in[0];
  const int* edge  = (const int*)d_in[1];
  const int* batch = (const int*)d_in[2];
  const float* W1l = (const float*)d_in[3];
  const float* b1l = (const float*)d_in[4];
  const float* W1r = (const float*)d_in[5];
  const float* W2l = (const float*)d_in[6];
  const float* b2l = (const float*)d_in[7];
  const float* W2r = (const float*)d_in[8];
  const float* W3l = (const float*)d_in[9];
  const float* b3l = (const float*)d_in[10];
  const float* W3r = (const float*)d_in[11];
  const float* Wlin = (const float*)d_in[12];
  const float* blin = (const float*)d_in[13];
  float* out = (float*)d_out;

  const int N = in_sizes[0] / 4;          // x: [N,1,4]
  const int E = in_sizes[1] / 2;          // edge_index: [2,E]
  const int B = out_size;
  const int rows = 4 * N;

  const int* srcA = edge;
  const int* dstA = edge + E;

  // workspace carve (~109 MB total)
  char* p = (char*)d_ws;
  auto carve = [&](size_t bytes) -> void* {
    void* r = (void*)p;
    p += (bytes + 255) & ~(size_t)255;
    return r;
  };
  int* rp      = (int*)carve((size_t)(N + 1) * 4);
  int* cursor  = (int*)carve((size_t)N * 4);
  int* bsum    = (int*)carve(4096);
  int* boff    = (int*)carve(4096);
  int* gcnt    = (int*)carve((size_t)B * 4);
  int* csr     = (int*)carve((size_t)E * 4);
  float* agg1  = (float*)carve((size_t)N * 4 * 4);
  float* pooled = (float*)carve((size_t)B * 256 * 4);
  ushort_t* Wb2l = (ushort_t*)carve(4096 * 2);
  ushort_t* Wb2r = (ushort_t*)carve(4096 * 2);
  ushort_t* Wb3l = (ushort_t*)carve(4096 * 2);
  ushort_t* Wb3r = (ushort_t*)carve(4096 * 2);
  ushort_t* hA = (ushort_t*)carve((size_t)N * 256 * 2);
  ushort_t* hB = (ushort_t*)carve((size_t)N * 256 * 2);
  (void)ws_size; (void)n_in;

  hipMemsetAsync(rp, 0, (size_t)N * 4, stream);
  hipMemsetAsync(gcnt, 0, (size_t)B * 4, stream);
  hipMemsetAsync(pooled, 0, (size_t)B * 256 * 4, stream);

  int nbScan = (N + TPB - 1) / TPB;

  k_hist<<<(E + TPB - 1) / TPB, TPB, 0, stream>>>(dstA, rp, E);
  k_gcnt<<<((N + 15) / 16 + TPB - 1) / TPB, TPB, 0, stream>>>(batch, gcnt, N);
  k_cvtw<<<16, TPB, 0, stream>>>(W2l, W2r, W3l, W3r, Wb2l, Wb2r, Wb3l, Wb3r, 4096);
  k_scan1<<<nbScan, TPB, 0, stream>>>(rp, bsum, N);
  k_scan2<<<1, 1024, 0, stream>>>(bsum, boff, nbScan);
  k_scan3<<<(N + 1 + TPB - 1) / TPB, TPB, 0, stream>>>(rp, boff, cursor, N, E);
  k_fill<<<(E + TPB - 1) / TPB, TPB, 0, stream>>>(srcA, dstA, cursor, csr, E);

  // layer 1 (F=1)
  k_agg1<<<(N + TPB - 1) / TPB, TPB, 0, stream>>>((const float4*)x, rp, csr, (float4*)agg1, N);
  k_l1<<<((size_t)rows * 8 + TPB - 1) / TPB, TPB, 0, stream>>>(x, agg1, W1l, b1l, W1r, hA, rows);

  // layers 2 & 3: fused gather + dual MFMA GEMM
  int nbLayer = (N + 15) / 16;
  k_layer<<<nbLayer, TPB, 0, stream>>>(hA, rp, csr, Wb2l, Wb2r, b2l, hB, N);
  k_layer<<<nbLayer, TPB, 0, stream>>>(hB, rp, csr, Wb3l, Wb3r, b3l, hA, N);

  // pooling + head
  k_pool<<<512, TPB, 0, stream>>>(hA, batch, pooled, N);
  k_final<<<(B * 4 + TPB - 1) / TPB, TPB, 0, stream>>>(pooled, gcnt, Wlin, blin, out, B);
}

// Round 4
// 473.436 us; speedup vs baseline: 13.9700x; 1.1191x over previous
//
#include <hip/hip_runtime.h>
#include <math.h>

#define TPB 256

typedef unsigned short ushort_t;
typedef __attribute__((ext_vector_type(8))) short short8v;     // 8 bf16 (4 VGPRs), MFMA A/B frag
typedef __attribute__((ext_vector_type(4))) float f32x4;       // MFMA C/D frag
typedef __attribute__((ext_vector_type(8))) unsigned short ushort8;

__device__ __forceinline__ float b2f(unsigned short u) {
  union { unsigned int i; float f; } c; c.i = ((unsigned int)u) << 16; return c.f;
}
__device__ __forceinline__ unsigned short f2b(float f) {
  union { float f; unsigned int i; } c; c.f = f;
  unsigned int x = c.i;
  x += 0x7FFFu + ((x >> 16) & 1u);           // round-to-nearest-even
  return (unsigned short)(x >> 16);
}

// ---------------- CSR build ----------------
__global__ void k_hist(const int* __restrict__ dst, int* deg, int E) {
  int e = blockIdx.x * TPB + threadIdx.x;
  if (e < E) atomicAdd(&deg[dst[e]], 1);
}

__global__ void k_gcnt(const int* __restrict__ batch, int* gcnt, int N) {
  int t = blockIdx.x * TPB + threadIdx.x;
  int n0 = t * 16;
  if (n0 >= N) return;
  int n1 = min(n0 + 16, N);
  int cur = batch[n0];
  int c = 0;
  for (int n = n0; n < n1; ++n) {
    int b = batch[n];
    if (b != cur) { atomicAdd(&gcnt[cur], c); cur = b; c = 0; }
    ++c;
  }
  atomicAdd(&gcnt[cur], c);
}

__global__ void k_scan1(int* data, int* bsum, int N) {
  __shared__ int s[TPB];
  int t = threadIdx.x;
  int i = blockIdx.x * TPB + t;
  int v = (i < N) ? data[i] : 0;
  s[t] = v;
  __syncthreads();
  for (int d = 1; d < TPB; d <<= 1) {
    int u = (t >= d) ? s[t - d] : 0;
    __syncthreads();
    s[t] += u;
    __syncthreads();
  }
  if (i < N) data[i] = s[t] - v;
  if (t == TPB - 1) bsum[blockIdx.x] = s[t];
}

__global__ void k_scan2(const int* bsum, int* boff, int nb) {
  __shared__ int s[1024];
  int t = threadIdx.x;
  int v = (t < nb) ? bsum[t] : 0;
  s[t] = v;
  __syncthreads();
  for (int d = 1; d < 1024; d <<= 1) {
    int u = (t >= d) ? s[t - d] : 0;
    __syncthreads();
    s[t] += u;
    __syncthreads();
  }
  if (t < nb) boff[t] = s[t] - v;
}

__global__ void k_scan3(int* rp, const int* __restrict__ boff, int* cursor, int N, int E) {
  int i = blockIdx.x * TPB + threadIdx.x;
  if (i < N) {
    int v = rp[i] + boff[i >> 8];
    rp[i] = v;
    cursor[i] = v;
  } else if (i == N) {
    rp[N] = E;
  }
}

__global__ void k_fill(const int* __restrict__ src, const int* __restrict__ dst,
                       int* cursor, int* __restrict__ csr, int E) {
  int e = blockIdx.x * TPB + threadIdx.x;
  if (e < E) {
    int p = atomicAdd(&cursor[dst[e]], 1);
    csr[p] = src[e];
  }
}

// ---------------- weight fp32 -> bf16 ----------------
__global__ void k_cvtw(const float* __restrict__ s0, const float* __restrict__ s1,
                       const float* __restrict__ s2, const float* __restrict__ s3,
                       ushort_t* d0, ushort_t* d1, ushort_t* d2, ushort_t* d3, int n) {
  int i = blockIdx.x * TPB + threadIdx.x;
  if (i < n) { d0[i] = f2b(s0[i]); d1[i] = f2b(s1[i]); d2[i] = f2b(s2[i]); d3[i] = f2b(s3[i]); }
}

// ---------------- Layer 1 (F=1) ----------------
__global__ void k_agg1(const float4* __restrict__ x, const int* __restrict__ rp,
                       const int* __restrict__ csr, float4* __restrict__ agg1, int N) {
  int n = blockIdx.x * TPB + threadIdx.x;
  if (n >= N) return;
  int b = rp[n], e = rp[n + 1];
  float4 a = make_float4(0.f, 0.f, 0.f, 0.f);
  int i = b;
  for (; i + 1 < e; i += 2) {
    float4 v0 = x[csr[i]];
    float4 v1 = x[csr[i + 1]];
    a.x += v0.x + v1.x; a.y += v0.y + v1.y;
    a.z += v0.z + v1.z; a.w += v0.w + v1.w;
  }
  if (i < e) {
    float4 v = x[csr[i]];
    a.x += v.x; a.y += v.y; a.z += v.z; a.w += v.w;
  }
  float inv = (e > b) ? 1.f / (float)(e - b) : 0.f;
  a.x *= inv; a.y *= inv; a.z *= inv; a.w *= inv;
  agg1[n] = a;
}

// h1 flat[(n*4+m)*64 + c] = relu(agg1[n*4+m]*W1l[c] + b1l[c] + x[n*4+m]*W1r[c]), bf16 out
__global__ void k_l1(const float* __restrict__ x, const float* __restrict__ agg1,
                     const float* __restrict__ W1l, const float* __restrict__ b1l,
                     const float* __restrict__ W1r, ushort_t* __restrict__ h, int rows) {
  int q = blockIdx.x * TPB + threadIdx.x;       // thread = (row, 8-col group)
  if (q >= rows * 8) return;
  int r = q >> 3, c8 = (q & 7) * 8;
  float a = agg1[r], xx = x[r];
  ushort8 o;
#pragma unroll
  for (int k = 0; k < 8; ++k) {
    float v = fmaxf(a * W1l[c8 + k] + b1l[c8 + k] + xx * W1r[c8 + k], 0.f);
    o[k] = f2b(v);
  }
  *(ushort8*)(h + (size_t)r * 64 + c8) = o;
}

// ---------------- Fused layer: mean-agg gather + dual MFMA GEMM + bias + relu ----------
// Block: 256 threads = 4 waves = 16 nodes = 64 GEMM rows. h flat viewed [4N][64] bf16.
// Gather: each wave splits into 4 groups of 16 lanes; group owns one node; lane owns
// 16 features (2x ushort8 loads per neighbor); neighbor loop unrolled x4 -> 8 loads
// in flight per lane. Requires N % 16 == 0 (true for N=100000).
__global__ __launch_bounds__(256) void k_layer(
    const ushort_t* __restrict__ hIn, const int* __restrict__ rp,
    const int* __restrict__ csr,
    const ushort_t* __restrict__ Wlb, const ushort_t* __restrict__ Wrb,
    const float* __restrict__ bias, ushort_t* __restrict__ hOut, int N) {
  __shared__ ushort_t As[4096];                 // [64 rows][64 bf16], 16B-unit XOR swizzle
  int t = threadIdx.x;
  int wave = t >> 6, lane = t & 63;
  int g = lane >> 4, l15 = lane & 15;           // group / lane-in-group
  int n0 = blockIdx.x * 16;
  int r0 = blockIdx.x * 64;
  int rows = N * 4;

  // ---- aggregation: group g of wave handles node nl = wave*4+g ----
  int nl = wave * 4 + g;
  int n = n0 + nl;
  int b = rp[n], e = rp[n + 1];
  const ushort_t* hsl = hIn + l15 * 16;         // lane's 16-feature slice

  float acc[16];
#pragma unroll
  for (int k = 0; k < 16; ++k) acc[k] = 0.f;

  int i = b;
  for (; i + 3 < e; i += 4) {
    int s0 = csr[i], s1 = csr[i + 1], s2 = csr[i + 2], s3 = csr[i + 3];
    const ushort8* p0 = (const ushort8*)(hsl + (size_t)s0 * 256);
    const ushort8* p1 = (const ushort8*)(hsl + (size_t)s1 * 256);
    const ushort8* p2 = (const ushort8*)(hsl + (size_t)s2 * 256);
    const ushort8* p3 = (const ushort8*)(hsl + (size_t)s3 * 256);
    ushort8 a0 = p0[0], b0 = p0[1];
    ushort8 a1 = p1[0], b1 = p1[1];
    ushort8 a2 = p2[0], b2 = p2[1];
    ushort8 a3 = p3[0], b3 = p3[1];
#pragma unroll
    for (int k = 0; k < 8; ++k) {
      acc[k]     += (b2f(a0[k]) + b2f(a1[k])) + (b2f(a2[k]) + b2f(a3[k]));
      acc[k + 8] += (b2f(b0[k]) + b2f(b1[k])) + (b2f(b2[k]) + b2f(b3[k]));
    }
  }
  for (; i < e; ++i) {
    const ushort8* p0 = (const ushort8*)(hsl + (size_t)csr[i] * 256);
    ushort8 a0 = p0[0], b0 = p0[1];
#pragma unroll
    for (int k = 0; k < 8; ++k) {
      acc[k]     += b2f(a0[k]);
      acc[k + 8] += b2f(b0[k]);
    }
  }

  {
    float inv = (e > b) ? 1.f / (float)(e - b) : 0.f;
    ushort8 pk0, pk1;
#pragma unroll
    for (int k = 0; k < 8; ++k) {
      pk0[k] = f2b(acc[k] * inv);
      pk1[k] = f2b(acc[k + 8] * inv);
    }
    // lane's features l15*16..+15 -> tile row nl*4 + (l15>>2), byte col (l15&3)*32
    int row = nl * 4 + (l15 >> 2);
    int cb = (l15 & 3) * 32;
    int xr = (row & 7) << 4;
    *(ushort8*)((char*)As + row * 128 + (cb ^ xr)) = pk0;
    *(ushort8*)((char*)As + row * 128 + ((cb + 16) ^ xr)) = pk1;
  }
  __syncthreads();

  // ---- fragments: A frag row=lane&15, k=(lane>>4)*8+e ----
  int arow = wave * 16 + l15;
  short8v af0 = *(const short8v*)((char*)As + arow * 128 + (((g * 16) + 0) ^ ((arow & 7) << 4)));
  short8v af1 = *(const short8v*)((char*)As + arow * 128 + (((g * 16) + 64) ^ ((arow & 7) << 4)));

  int rbase = r0 + wave * 16 + l15;
  const ushort_t* hrow = hIn + (size_t)rbase * 64;
  short8v hf0 = *(const short8v*)(hrow + g * 8);
  short8v hf1 = *(const short8v*)(hrow + 32 + g * 8);

  f32x4 fac[4];
#pragma unroll
  for (int c = 0; c < 4; ++c) {
    float bv = bias[c * 16 + l15];
    fac[c] = (f32x4){bv, bv, bv, bv};
    const ushort_t* wl = Wlb + (size_t)(c * 16 + l15) * 64;
    const ushort_t* wr = Wrb + (size_t)(c * 16 + l15) * 64;
    short8v bl0 = *(const short8v*)(wl + g * 8);
    short8v bl1 = *(const short8v*)(wl + 32 + g * 8);
    short8v br0 = *(const short8v*)(wr + g * 8);
    short8v br1 = *(const short8v*)(wr + 32 + g * 8);
    fac[c] = __builtin_amdgcn_mfma_f32_16x16x32_bf16(af0, bl0, fac[c], 0, 0, 0);
    fac[c] = __builtin_amdgcn_mfma_f32_16x16x32_bf16(af1, bl1, fac[c], 0, 0, 0);
    fac[c] = __builtin_amdgcn_mfma_f32_16x16x32_bf16(hf0, br0, fac[c], 0, 0, 0);
    fac[c] = __builtin_amdgcn_mfma_f32_16x16x32_bf16(hf1, br1, fac[c], 0, 0, 0);
  }

  // ---- C/D: col = lane&15, row = (lane>>4)*4 + reg ----
#pragma unroll
  for (int c = 0; c < 4; ++c) {
#pragma unroll
    for (int i2 = 0; i2 < 4; ++i2) {
      int grow = r0 + wave * 16 + g * 4 + i2;
      hOut[(size_t)grow * 64 + c * 16 + l15] = f2b(fmaxf(fac[c][i2], 0.f));
    }
  }
}

// ---------------- Pooling (batch sorted: run-length accumulate), bf16 in ----------------
__global__ void k_pool(const ushort_t* __restrict__ h, const int* __restrict__ batch,
                       float* pooled, int N) {
  int t = threadIdx.x;
  int nPer = (N + gridDim.x - 1) / gridDim.x;
  int n0 = blockIdx.x * nPer;
  int n1 = min(N, n0 + nPer);
  if (n0 >= n1) return;
  float acc = 0.f;
  int cur = batch[n0];
  for (int n = n0; n < n1; ++n) {
    int b = batch[n];
    if (b != cur) {
      atomicAdd(&pooled[cur * 256 + t], acc);
      acc = 0.f;
      cur = b;
    }
    acc += b2f(h[(size_t)n * 256 + t]);
  }
  atomicAdd(&pooled[cur * 256 + t], acc);
}

__global__ void k_final(const float* __restrict__ pooled, const int* __restrict__ gcnt,
                        const float* __restrict__ Wlin, const float* __restrict__ blin,
                        float* __restrict__ out, int B) {
  int t = blockIdx.x * TPB + threadIdx.x;
  int b = t >> 2, j = t & 3;
  if (b >= B) return;
  float inv = 1.f / fmaxf((float)gcnt[b], 1.f);
  float s = blin[0];
  const float* p = pooled + b * 256 + j * 64;
#pragma unroll
  for (int f = 0; f < 64; ++f) s += p[f] * inv * Wlin[f];
  float z = 1.f / (1.f + expf(-s));
  z += __shfl_xor(z, 1);
  z += __shfl_xor(z, 2);
  if (j == 0) out[b] = 0.25f * z;
}

// ---------------- Host launcher ----------------
extern "C" void kernel_launch(void* const* d_in, const int* in_sizes, int n_in,
                              void* d_out, int out_size, void* d_ws, size_t ws_size,
                              hipStream_t stream) {
  const float* x   = (const float*)d_in[0];
  const int* edge  = (const int*)d_in[1];
  const int* batch = (const int*)d_in[2];
  const float* W1l = (const float*)d_in[3];
  const float* b1l = (const float*)d_in[4];
  const float* W1r = (const float*)d_in[5];
  const float* W2l = (const float*)d_in[6];
  const float* b2l = (const float*)d_in[7];
  const float* W2r = (const float*)d_in[8];
  const float* W3l = (const float*)d_in[9];
  const float* b3l = (const float*)d_in[10];
  const float* W3r = (const float*)d_in[11];
  const float* Wlin = (const float*)d_in[12];
  const float* blin = (const float*)d_in[13];
  float* out = (float*)d_out;

  const int N = in_sizes[0] / 4;          // x: [N,1,4]
  const int E = in_sizes[1] / 2;          // edge_index: [2,E]
  const int B = out_size;
  const int rows = 4 * N;

  const int* srcA = edge;
  const int* dstA = edge + E;

  // workspace carve (~109 MB total)
  char* p = (char*)d_ws;
  auto carve = [&](size_t bytes) -> void* {
    void* r = (void*)p;
    p += (bytes + 255) & ~(size_t)255;
    return r;
  };
  int* rp      = (int*)carve((size_t)(N + 1) * 4);
  int* cursor  = (int*)carve((size_t)N * 4);
  int* bsum    = (int*)carve(4096);
  int* boff    = (int*)carve(4096);
  int* gcnt    = (int*)carve((size_t)B * 4);
  int* csr     = (int*)carve((size_t)E * 4);
  float* agg1  = (float*)carve((size_t)N * 4 * 4);
  float* pooled = (float*)carve((size_t)B * 256 * 4);
  ushort_t* Wb2l = (ushort_t*)carve(4096 * 2);
  ushort_t* Wb2r = (ushort_t*)carve(4096 * 2);
  ushort_t* Wb3l = (ushort_t*)carve(4096 * 2);
  ushort_t* Wb3r = (ushort_t*)carve(4096 * 2);
  ushort_t* hA = (ushort_t*)carve((size_t)N * 256 * 2);
  ushort_t* hB = (ushort_t*)carve((size_t)N * 256 * 2);
  (void)ws_size; (void)n_in;

  hipMemsetAsync(rp, 0, (size_t)N * 4, stream);
  hipMemsetAsync(gcnt, 0, (size_t)B * 4, stream);
  hipMemsetAsync(pooled, 0, (size_t)B * 256 * 4, stream);

  int nbScan = (N + TPB - 1) / TPB;

  k_hist<<<(E + TPB - 1) / TPB, TPB, 0, stream>>>(dstA, rp, E);
  k_gcnt<<<((N + 15) / 16 + TPB - 1) / TPB, TPB, 0, stream>>>(batch, gcnt, N);
  k_cvtw<<<16, TPB, 0, stream>>>(W2l, W2r, W3l, W3r, Wb2l, Wb2r, Wb3l, Wb3r, 4096);
  k_scan1<<<nbScan, TPB, 0, stream>>>(rp, bsum, N);
  k_scan2<<<1, 1024, 0, stream>>>(bsum, boff, nbScan);
  k_scan3<<<(N + 1 + TPB - 1) / TPB, TPB, 0, stream>>>(rp, boff, cursor, N, E);
  k_fill<<<(E + TPB - 1) / TPB, TPB, 0, stream>>>(srcA, dstA, cursor, csr, E);

  // layer 1 (F=1)
  k_agg1<<<(N + TPB - 1) / TPB, TPB, 0, stream>>>((const float4*)x, rp, csr, (float4*)agg1, N);
  k_l1<<<((size_t)rows * 8 + TPB - 1) / TPB, TPB, 0, stream>>>(x, agg1, W1l, b1l, W1r, hA, rows);

  // layers 2 & 3: fused gather + dual MFMA GEMM
  int nbLayer = (N + 15) / 16;
  k_layer<<<nbLayer, TPB, 0, stream>>>(hA, rp, csr, Wb2l, Wb2r, b2l, hB, N);
  k_layer<<<nbLayer, TPB, 0, stream>>>(hB, rp, csr, Wb3l, Wb3r, b3l, hA, N);

  // pooling + head
  k_pool<<<512, TPB, 0, stream>>>(hA, batch, pooled, N);
  k_final<<<(B * 4 + TPB - 1) / TPB, TPB, 0, stream>>>(pooled, gcnt, Wlin, blin, out, B);
}